// Round 7
// baseline (757.230 us; speedup 1.0000x reference)
//
#include <hip/hip_runtime.h>

typedef __attribute__((ext_vector_type(8))) short short8;
typedef __attribute__((ext_vector_type(4))) float f32x4;
typedef __attribute__((ext_vector_type(4))) unsigned int u32x4;

#define MFMA16(a, b, c) __builtin_amdgcn_mfma_f32_16x16x32_bf16((a), (b), (c), 0, 0, 0)

__device__ __forceinline__ unsigned short f2bf(float f) {
  unsigned int u = __builtin_bit_cast(unsigned int, f);
  u += 0x7fffu + ((u >> 16) & 1u);   // RNE
  return (unsigned short)(u >> 16);
}
__device__ __forceinline__ float bf2f(unsigned short s) {
  unsigned int u = ((unsigned int)s) << 16;
  return __builtin_bit_cast(float, u);
}
// Packed f32->bf16 RNE (1 instr for 2 values); no builtin on gfx950.
__device__ __forceinline__ unsigned cvtpk(float lo, float hi) {
  unsigned r;
  asm("v_cvt_pk_bf16_f32 %0, %1, %2" : "=v"(r) : "v"(lo), "v"(hi));
  return r;
}

// Fused LSTM element update, bias folded into the exp2 fmas.
//   sig(i)*tanh(g) = (B-1)/((1+A)(1+B)),  A=2^(-L1*i), B=2^(L2*g)
//   h = sig(o)*tanh(c) = (C-1)/((1+O)(1+C))
__device__ __forceinline__ void lstm_elem(float gi, float gf, float gg, float go,
                                          float nbi, float nbf, float pbg, float nbo,
                                          float& c, float& h) {
  const float L1 = 1.44269504f, L2 = 2.88539008f;
  float A = __builtin_amdgcn_exp2f(__builtin_fmaf(-L1, gi, nbi));
  float B = __builtin_amdgcn_exp2f(__builtin_fmaf(L2, gg, pbg));
  float t1 = 1.0f + B;
  float den = __builtin_amdgcn_rcpf(__builtin_fmaf(A, t1, t1));
  float it = (B - 1.0f) * den;                       // sig(i)*tanh(g)
  float F = __builtin_amdgcn_rcpf(1.0f + __builtin_amdgcn_exp2f(__builtin_fmaf(-L1, gf, nbf)));
  c = __builtin_fmaf(F, c, it);
  float C = __builtin_amdgcn_exp2f(L2 * c);
  float O = __builtin_amdgcn_exp2f(__builtin_fmaf(-L1, go, nbo));
  float t2 = 1.0f + C;
  float den2 = __builtin_amdgcn_rcpf(__builtin_fmaf(O, t2, t2));
  h = (C - 1.0f) * den2;                             // sig(o)*tanh(c)
}

// ---------------------------------------------------------------------------
// Prep: swizzle weights into MFMA B-fragment-linear bf16 layout.
// ---------------------------------------------------------------------------
__global__ void prep_weights(const float* __restrict__ w_ih_l0, const float* __restrict__ w_hh_l0,
                             const float* __restrict__ w_ih_l1, const float* __restrict__ w_hh_l1,
                             unsigned short* __restrict__ W0f, unsigned short* __restrict__ W1f) {
  int tid = blockIdx.x * blockDim.x + threadIdx.x;
  if (tid < 32 * 5 * 64) {
    int nt = tid / 320, rem = tid % 320;
    int kc = rem / 64, lane = rem % 64;
    int g = nt * 16 + (lane & 15);
    int k0 = kc * 32 + (lane >> 4) * 8;
    short8 s;
#pragma unroll
    for (int j = 0; j < 8; ++j) {
      int k = k0 + j;
      float val;
      if (k < 28) val = w_ih_l0[g * 28 + k];
      else if (k < 32) val = 0.0f;
      else val = w_hh_l0[g * 128 + (k - 32)];
      s[j] = (short)f2bf(val);
    }
    *(short8*)(W0f + (size_t)tid * 8) = s;
  } else if (tid < 32 * 5 * 64 + 32 * 8 * 64) {
    int id = tid - 32 * 5 * 64;
    int nt = id / 512, rem = id % 512;
    int kc = rem / 64, lane = rem % 64;
    int g = nt * 16 + (lane & 15);
    int k0 = kc * 32 + (lane >> 4) * 8;
    short8 s;
#pragma unroll
    for (int j = 0; j < 8; ++j) {
      int k = k0 + j;
      float val = (k < 128) ? w_ih_l1[g * 128 + k] : w_hh_l1[g * 128 + (k - 128)];
      s[j] = (short)f2bf(val);
    }
    *(short8*)(W1f + (size_t)id * 8) = s;
  }
}

// ---------------------------------------------------------------------------
// Fused 2-layer LSTM. 256 blocks x 512 threads (8 waves) = 1 block/CU.
// Block owns 64 batch rows x 28 t; wave wv = n-slice (16 h-cols x 4 gates).
//
// vs 277us version (MfmaUtil 32 + VALUBusy 48 SEQUENTIAL, barrier lock-step):
// PHASE ROTATION so every trans-heavy epilogue sits beside an independent
// MFMA stream in one basic block (intra-wave MFMA||VALU overlap):
//   phase1: E0(t) || A1b(t)   [L1 mfma kc4-7, reads h1(t-1) seg1[q]]
//   bar1  (h0(t) visible)
//   phase2: A1a(t)            [L1 mfma kc0-3, reads h0(t) seg0[p]]
//   phase3: E1(t) || A0(t+1)  [L0 mfma, reads h0(t) seg0[p] + x(t+1)]
//   bar2  (h1(t) visible)
// Hazard matrix (seg0[P]=h0 at P=t&1, seg1[P]=h1): E0(t+1) W seg0[q] vs last
// R by A0(t)/A1a(t-1): >=2 barriers apart. E1(t+1) W seg1[q] vs R A1b(t):
// bar1/2(t)+bar1(t+1) apart. A1b(t+1) R seg1[p] after bar2(t) W E1(t). OK.
// Manual prefetch arrays dropped (spill was ~free but bought nothing, R6);
// each MFMA block's loads issue at block top, covered by the paired epilogue.
// LDS segments (bytes): seg(layer,p) = (layer*2+p)*16384; 64 KiB total.
// element (row,col) of seg: byte = row*256 + (((col>>3)^(row&15))<<4) + (col&7)*2
// ---------------------------------------------------------------------------
__global__ __launch_bounds__(512) void lstm_fused(
    const float* __restrict__ x,
    const float* __restrict__ b_ih_l0, const float* __restrict__ b_hh_l0,
    const float* __restrict__ b_ih_l1, const float* __restrict__ b_hh_l1,
    const float* __restrict__ fc_w, const float* __restrict__ fc_b,
    const unsigned short* __restrict__ W0f, const unsigned short* __restrict__ W1f,
    float* __restrict__ out) {
  __shared__ __align__(16) char hls[4 * 16384];

  const int tid = (int)threadIdx.x;
  const int wv = tid >> 6;          // wave 0..7 = n-slice
  const int lane = tid & 63;
  const int lr = lane & 15;         // A: m-row / B: n-col / D: col
  const int lq = lane >> 4;         // k-quad / D row group
  const int b0 = (int)blockIdx.x * 64;

  for (int i = tid; i < 16384; i += 512) ((unsigned*)hls)[i] = 0u;

  // Premultiplied bias scalars: q0/q1/q3 -> -L1*b, q2 -> +L2*b.
  const float L1 = 1.44269504f, L2 = 2.88539008f;
  float nb0[4], nb1[4];
#pragma unroll
  for (int q = 0; q < 4; ++q) {
    int g = q * 128 + wv * 16 + lr;
    float s0 = b_ih_l0[g] + b_hh_l0[g];
    float s1 = b_ih_l1[g] + b_hh_l1[g];
    float sc = (q == 2) ? L2 : -L1;
    nb0[q] = sc * s0;
    nb1[q] = sc * s1;
  }
  const f32x4 zero4 = {0.0f, 0.0f, 0.0f, 0.0f};

  // Read base (A-frag, row m*16+lr, k-chunk kc): addr = (rbB+seg) ^ (kc<<6) + m*4096
  const unsigned rbB = (unsigned)(lr * 256 + ((lq ^ lr) << 4));
  // Write base (D elem row m*16+lq*4+r): addr = (wbB+seg) ^ (r<<4) + m*4096 + r*256
  const unsigned cwl = (unsigned)((wv * 2 + (lr >> 3)) ^ (lq << 2));
  const unsigned wbB = (unsigned)(lq * 1024 + (cwl << 4) + (lr & 7) * 2);
  // Weight byte-offset bases (32-bit; q/kc strides are compile-time).
  const unsigned wB0 = (unsigned)((wv * 320 + lane) * 16);
  const unsigned wB1 = (unsigned)((wv * 512 + lane) * 16);
  const unsigned xo0 = (unsigned)(((b0 + lr) * 784 + lq * 8) * 4);

  float c0s[4][4], c1s[4][4];   // [m][r]
#pragma unroll
  for (int m = 0; m < 4; ++m)
#pragma unroll
    for (int r = 0; r < 4; ++r) { c0s[m][r] = 0.0f; c1s[m][r] = 0.0f; }

  f32x4 acc0[4][4], acc1[4][4];   // [m][q]

  __syncthreads();

  // ---- Prologue: A0(0). h0(-1)=0 so kc1-4 contribute nothing: skip them. --
  {
    short8 ax[4];
#pragma unroll
    for (int m = 0; m < 4; ++m) {
      const unsigned xo = xo0 + (unsigned)(m * 50176);
      f32x4 u0 = *(const f32x4*)((const char*)x + xo);
      f32x4 u1 = {0.0f, 0.0f, 0.0f, 0.0f};
      if (lq < 3) u1 = *(const f32x4*)((const char*)x + xo + 16);
      u32x4 up;
      up[0] = cvtpk(u0[0], u0[1]);
      up[1] = cvtpk(u0[2], u0[3]);
      up[2] = cvtpk(u1[0], u1[1]);
      up[3] = cvtpk(u1[2], u1[3]);
      ax[m] = __builtin_bit_cast(short8, up);
    }
    short8 bq[4];
#pragma unroll
    for (int q = 0; q < 4; ++q)
      bq[q] = *(const short8*)((const char*)W0f + (wB0 + (unsigned)(q * 40960)));
#pragma unroll
    for (int m = 0; m < 4; ++m)
#pragma unroll
      for (int q = 0; q < 4; ++q) acc0[m][q] = MFMA16(ax[m], bq[q], zero4);
  }

  for (int t = 0; t < 28; ++t) {
    const unsigned sp = (unsigned)(t & 1) << 14;   // seg offset, parity p
    const unsigned sq = sp ^ 16384u;               // parity 1-p

    // ======== phase 1: E0(t) -> seg0[p]  ||  A1b(t): acc1 = h1(t-1)@W1hh ==
    {
      const unsigned rh1 = rbB + 32768u + sq;
      const unsigned wa = wbB + sp;
#pragma unroll
      for (int j = 0; j < 4; ++j) {
        // A1b chunk kc=4+j (j==0 initializes acc1 via C=zero4)
        short8 bq[4];
#pragma unroll
        for (int q = 0; q < 4; ++q)
          bq[q] = *(const short8*)((const char*)W1f + (wB1 + (unsigned)(q * 65536 + (4 + j) * 1024)));
        short8 am[4];
#pragma unroll
        for (int m = 0; m < 4; ++m)
          am[m] = *(const short8*)(hls + ((rh1 ^ (unsigned)(j * 64)) + m * 4096));
        if (j == 0) {
#pragma unroll
          for (int m = 0; m < 4; ++m)
#pragma unroll
            for (int q = 0; q < 4; ++q) acc1[m][q] = MFMA16(am[m], bq[q], zero4);
        } else {
#pragma unroll
          for (int m = 0; m < 4; ++m)
#pragma unroll
            for (int q = 0; q < 4; ++q) acc1[m][q] = MFMA16(am[m], bq[q], acc1[m][q]);
        }
        // E0 m-tile j (independent of A1b; scheduler meshes trans with MFMA)
        float hv[4];
#pragma unroll
        for (int r = 0; r < 4; ++r) {
          float c = c0s[j][r], h;
          lstm_elem(acc0[j][0][r], acc0[j][1][r], acc0[j][2][r], acc0[j][3][r],
                    nb0[0], nb0[1], nb0[2], nb0[3], c, h);
          c0s[j][r] = c; hv[r] = h;
        }
        unsigned u01 = cvtpk(hv[0], hv[1]);
        unsigned u23 = cvtpk(hv[2], hv[3]);
        *(unsigned short*)(hls + ((wa ^ 0u)  + j * 4096 + 0))   = (unsigned short)u01;
        *(unsigned short*)(hls + ((wa ^ 16u) + j * 4096 + 256)) = (unsigned short)(u01 >> 16);
        *(unsigned short*)(hls + ((wa ^ 32u) + j * 4096 + 512)) = (unsigned short)u23;
        *(unsigned short*)(hls + ((wa ^ 48u) + j * 4096 + 768)) = (unsigned short)(u23 >> 16);
      }
    }

    __syncthreads();   // bar1: h0(t) visible (also separates seg WAR pairs)

    // ======== phase 2: A1a(t): acc1 += h0(t)@W1ih (seg0[p]) ===============
    {
      const unsigned rh0 = rbB + sp;
#pragma unroll 2
      for (int kc = 0; kc < 4; ++kc) {
        short8 bq[4];
#pragma unroll
        for (int q = 0; q < 4; ++q)
          bq[q] = *(const short8*)((const char*)W1f + (wB1 + (unsigned)(q * 65536 + kc * 1024)));
        short8 am[4];
#pragma unroll
        for (int m = 0; m < 4; ++m)
          am[m] = *(const short8*)(hls + ((rh0 ^ (unsigned)(kc * 64)) + m * 4096));
#pragma unroll
        for (int m = 0; m < 4; ++m)
#pragma unroll
          for (int q = 0; q < 4; ++q) acc1[m][q] = MFMA16(am[m], bq[q], acc1[m][q]);
      }
    }

    // ======== phase 3: E1(t) -> seg1[p]  ||  A0(t+1) from h0(t)+x(t+1) ====
    {
      const unsigned wa = wbB + 32768u + sp;
      if (t < 27) {
        // A0 kc0: x(t+1) fragment (global loads issue at block top)
        const char* xb = (const char*)x + (unsigned)((t + 1) * 112);
        short8 ax[4];
#pragma unroll
        for (int m = 0; m < 4; ++m) {
          const unsigned xo = xo0 + (unsigned)(m * 50176);
          f32x4 u0 = *(const f32x4*)(xb + xo);
          f32x4 u1 = {0.0f, 0.0f, 0.0f, 0.0f};
          if (lq < 3) u1 = *(const f32x4*)(xb + xo + 16);
          u32x4 up;
          up[0] = cvtpk(u0[0], u0[1]);
          up[1] = cvtpk(u0[2], u0[3]);
          up[2] = cvtpk(u1[0], u1[1]);
          up[3] = cvtpk(u1[2], u1[3]);
          ax[m] = __builtin_bit_cast(short8, up);
        }
        short8 bq0[4];
#pragma unroll
        for (int q = 0; q < 4; ++q)
          bq0[q] = *(const short8*)((const char*)W0f + (wB0 + (unsigned)(q * 40960)));
#pragma unroll
        for (int m = 0; m < 4; ++m)
#pragma unroll
          for (int q = 0; q < 4; ++q) acc0[m][q] = MFMA16(ax[m], bq0[q], zero4);

        const unsigned r0 = rbB + sp;   // h0(t) in seg0[p]
#pragma unroll
        for (int j = 0; j < 4; ++j) {
          // A0 chunk kc=1+j
          short8 bq[4];
#pragma unroll
          for (int q = 0; q < 4; ++q)
            bq[q] = *(const short8*)((const char*)W0f + (wB0 + (unsigned)(q * 40960 + (1 + j) * 1024)));
          short8 am[4];
#pragma unroll
          for (int m = 0; m < 4; ++m)
            am[m] = *(const short8*)(hls + ((r0 ^ (unsigned)(j * 64)) + m * 4096));
#pragma unroll
          for (int m = 0; m < 4; ++m)
#pragma unroll
            for (int q = 0; q < 4; ++q) acc0[m][q] = MFMA16(am[m], bq[q], acc0[m][q]);
          // E1 m-tile j
          float hv[4];
#pragma unroll
          for (int r = 0; r < 4; ++r) {
            float c = c1s[j][r], h;
            lstm_elem(acc1[j][0][r], acc1[j][1][r], acc1[j][2][r], acc1[j][3][r],
                      nb1[0], nb1[1], nb1[2], nb1[3], c, h);
            c1s[j][r] = c; hv[r] = h;
          }
          unsigned u01 = cvtpk(hv[0], hv[1]);
          unsigned u23 = cvtpk(hv[2], hv[3]);
          *(unsigned short*)(hls + ((wa ^ 0u)  + j * 4096 + 0))   = (unsigned short)u01;
          *(unsigned short*)(hls + ((wa ^ 16u) + j * 4096 + 256)) = (unsigned short)(u01 >> 16);
          *(unsigned short*)(hls + ((wa ^ 32u) + j * 4096 + 512)) = (unsigned short)u23;
          *(unsigned short*)(hls + ((wa ^ 48u) + j * 4096 + 768)) = (unsigned short)(u23 >> 16);
        }
      } else {
        // t == 27: E1 only
#pragma unroll
        for (int j = 0; j < 4; ++j) {
          float hv[4];
#pragma unroll
          for (int r = 0; r < 4; ++r) {
            float c = c1s[j][r], h;
            lstm_elem(acc1[j][0][r], acc1[j][1][r], acc1[j][2][r], acc1[j][3][r],
                      nb1[0], nb1[1], nb1[2], nb1[3], c, h);
            c1s[j][r] = c; hv[r] = h;
          }
          unsigned u01 = cvtpk(hv[0], hv[1]);
          unsigned u23 = cvtpk(hv[2], hv[3]);
          *(unsigned short*)(hls + ((wa ^ 0u)  + j * 4096 + 0))   = (unsigned short)u01;
          *(unsigned short*)(hls + ((wa ^ 16u) + j * 4096 + 256)) = (unsigned short)(u01 >> 16);
          *(unsigned short*)(hls + ((wa ^ 32u) + j * 4096 + 512)) = (unsigned short)u23;
          *(unsigned short*)(hls + ((wa ^ 48u) + j * 4096 + 768)) = (unsigned short)(u23 >> 16);
        }
      }
    }

    __syncthreads();   // bar2: h1(t) visible
  }

  // ---------------- final h_n / c_n stores --------------------------------
  // t=27 parity p=1: h0(27) in seg0[1] = +16384, h1(27) in seg1[1] = +49152.
  {
    const unsigned wa0 = wbB + 16384u;
    const unsigned wa1 = wbB + 49152u;
#pragma unroll
    for (int m = 0; m < 4; ++m)
#pragma unroll
      for (int r = 0; r < 4; ++r) {
        int row = m * 16 + lq * 4 + r, col = wv * 16 + lr;
        size_t o = (size_t)(b0 + row) * 128 + col;
        unsigned roff = (unsigned)(r << 4);
        float h0 = bf2f(*(const unsigned short*)(hls + ((wa0 ^ roff) + m * 4096 + r * 256)));
        float h1 = bf2f(*(const unsigned short*)(hls + ((wa1 ^ roff) + m * 4096 + r * 256)));
        out[163840 + o] = h0;            // h_n layer 0
        out[4358144 + o] = c0s[m][r];    // c_n layer 0
        out[2260992 + o] = h1;           // h_n layer 1
        out[6455296 + o] = c1s[m][r];    // c_n layer 1
      }
  }

  // ---------------- logits = h1(27) @ fc_w^T + fc_b ------------------------
  // bar2(27) already made seg1[1] visible to all threads.
  for (int it = tid; it < 640; it += 512) {
    const unsigned short* h1f = (const unsigned short*)(hls + 49152);
    int bl = it / 10, o = it % 10;
    float s = fc_b[o];
#pragma unroll
    for (int kc8 = 0; kc8 < 16; ++kc8) {
      short8 hv = *(const short8*)(h1f + bl * 128 + ((kc8 ^ (bl & 15)) << 3));
      const float* wp = fc_w + o * 128 + kc8 * 8;
#pragma unroll
      for (int j = 0; j < 8; ++j) s += bf2f((unsigned short)hv[j]) * wp[j];
    }
    out[(size_t)(b0 + bl) * 10 + o] = s;
  }
}

extern "C" void kernel_launch(void* const* d_in, const int* in_sizes, int n_in,
                              void* d_out, int out_size, void* d_ws, size_t ws_size,
                              hipStream_t stream) {
  const float* x       = (const float*)d_in[0];
  const float* w_ih_l0 = (const float*)d_in[1];
  const float* w_hh_l0 = (const float*)d_in[2];
  const float* b_ih_l0 = (const float*)d_in[3];
  const float* b_hh_l0 = (const float*)d_in[4];
  const float* w_ih_l1 = (const float*)d_in[5];
  const float* w_hh_l1 = (const float*)d_in[6];
  const float* b_ih_l1 = (const float*)d_in[7];
  const float* b_hh_l1 = (const float*)d_in[8];
  const float* fc_w    = (const float*)d_in[9];
  const float* fc_b    = (const float*)d_in[10];

  unsigned short* W0f = (unsigned short*)d_ws;            // 32*5*64*8 = 81920 ush
  unsigned short* W1f = W0f + 32 * 5 * 64 * 8;            // 32*8*64*8 = 131072 ush
  float* out = (float*)d_out;

  hipLaunchKernelGGL(prep_weights, dim3(104), dim3(256), 0, stream,
                     w_ih_l0, w_hh_l0, w_ih_l1, w_hh_l1, W0f, W1f);
  hipLaunchKernelGGL(lstm_fused, dim3(256), dim3(512), 0, stream,
                     x, b_ih_l0, b_hh_l0, b_ih_l1, b_hh_l1, fc_w, fc_b, W0f, W1f, out);
}

// Round 8
// 332.717 us; speedup vs baseline: 2.2759x; 2.2759x over previous
//
#include <hip/hip_runtime.h>

typedef __attribute__((ext_vector_type(8))) short short8;
typedef __attribute__((ext_vector_type(4))) float f32x4;
typedef __attribute__((ext_vector_type(4))) unsigned int u32x4;

#define MFMA16(a, b, c) __builtin_amdgcn_mfma_f32_16x16x32_bf16((a), (b), (c), 0, 0, 0)

// LDS-only barrier: __syncthreads() drains vmcnt(0) too, killing in-flight
// global prefetches at every barrier. We only need LDS visibility: drain
// lgkmcnt (own ds_writes), fence the scheduler (rule: hipcc can hoist
// reg-only ops past inline-asm waits), then s_barrier. vmcnt loads are
// register-dest, consumed by this wave only -> compiler's use-site waits
// are sufficient.
#define BAR_LDS()                                                  \
  do {                                                             \
    asm volatile("s_waitcnt lgkmcnt(0)" ::: "memory");             \
    __builtin_amdgcn_sched_barrier(0);                             \
    __builtin_amdgcn_s_barrier();                                  \
    __builtin_amdgcn_sched_barrier(0);                             \
  } while (0)

__device__ __forceinline__ unsigned short f2bf(float f) {
  unsigned int u = __builtin_bit_cast(unsigned int, f);
  u += 0x7fffu + ((u >> 16) & 1u);   // RNE
  return (unsigned short)(u >> 16);
}
__device__ __forceinline__ float bf2f(unsigned short s) {
  unsigned int u = ((unsigned int)s) << 16;
  return __builtin_bit_cast(float, u);
}
// Packed f32->bf16 RNE (1 instr for 2 values); no builtin on gfx950.
__device__ __forceinline__ unsigned cvtpk(float lo, float hi) {
  unsigned r;
  asm("v_cvt_pk_bf16_f32 %0, %1, %2" : "=v"(r) : "v"(lo), "v"(hi));
  return r;
}

// Fused LSTM element update, bias folded into the exp2 fmas.
//   sig(i)*tanh(g) = (B-1)/((1+A)(1+B)),  A=2^(-L1*i), B=2^(L2*g)
//   h = sig(o)*tanh(c) = (C-1)/((1+O)(1+C))
__device__ __forceinline__ void lstm_elem(float gi, float gf, float gg, float go,
                                          float nbi, float nbf, float pbg, float nbo,
                                          float& c, float& h) {
  const float L1 = 1.44269504f, L2 = 2.88539008f;
  float A = __builtin_amdgcn_exp2f(__builtin_fmaf(-L1, gi, nbi));
  float B = __builtin_amdgcn_exp2f(__builtin_fmaf(L2, gg, pbg));
  float t1 = 1.0f + B;
  float den = __builtin_amdgcn_rcpf(__builtin_fmaf(A, t1, t1));
  float it = (B - 1.0f) * den;                       // sig(i)*tanh(g)
  float F = __builtin_amdgcn_rcpf(1.0f + __builtin_amdgcn_exp2f(__builtin_fmaf(-L1, gf, nbf)));
  c = __builtin_fmaf(F, c, it);
  float C = __builtin_amdgcn_exp2f(L2 * c);
  float O = __builtin_amdgcn_exp2f(__builtin_fmaf(-L1, go, nbo));
  float t2 = 1.0f + C;
  float den2 = __builtin_amdgcn_rcpf(__builtin_fmaf(O, t2, t2));
  h = (C - 1.0f) * den2;                             // sig(o)*tanh(c)
}

// ---------------------------------------------------------------------------
// Prep: swizzle weights into MFMA B-fragment-linear bf16 layout.
// ---------------------------------------------------------------------------
__global__ void prep_weights(const float* __restrict__ w_ih_l0, const float* __restrict__ w_hh_l0,
                             const float* __restrict__ w_ih_l1, const float* __restrict__ w_hh_l1,
                             unsigned short* __restrict__ W0f, unsigned short* __restrict__ W1f) {
  int tid = blockIdx.x * blockDim.x + threadIdx.x;
  if (tid < 32 * 5 * 64) {
    int nt = tid / 320, rem = tid % 320;
    int kc = rem / 64, lane = rem % 64;
    int g = nt * 16 + (lane & 15);
    int k0 = kc * 32 + (lane >> 4) * 8;
    short8 s;
#pragma unroll
    for (int j = 0; j < 8; ++j) {
      int k = k0 + j;
      float val;
      if (k < 28) val = w_ih_l0[g * 28 + k];
      else if (k < 32) val = 0.0f;
      else val = w_hh_l0[g * 128 + (k - 32)];
      s[j] = (short)f2bf(val);
    }
    *(short8*)(W0f + (size_t)tid * 8) = s;
  } else if (tid < 32 * 5 * 64 + 32 * 8 * 64) {
    int id = tid - 32 * 5 * 64;
    int nt = id / 512, rem = id % 512;
    int kc = rem / 64, lane = rem % 64;
    int g = nt * 16 + (lane & 15);
    int k0 = kc * 32 + (lane >> 4) * 8;
    short8 s;
#pragma unroll
    for (int j = 0; j < 8; ++j) {
      int k = k0 + j;
      float val = (k < 128) ? w_ih_l1[g * 128 + k] : w_hh_l1[g * 128 + (k - 128)];
      s[j] = (short)f2bf(val);
    }
    *(short8*)(W1f + (size_t)id * 8) = s;
  }
}

// ---------------------------------------------------------------------------
// Fused 2-layer LSTM. 256 blocks x 512 threads (8 waves) = 1 block/CU.
// Block owns 64 batch rows x 28 timesteps; wave wv = n-slice.
//
// Base = proven 278us kernel (R4 structure). R7's two-acc phase rotation is
// UNAFFORDABLE at the 128-VGPR clamp (spilled accumulators -> 1.8 GB scratch,
// 686us) - do not revisit without halving per-wave acc.
// This round's single change: hot-loop barrier = BAR_LDS() (lgkm-only drain)
// so the pq / pw0+xu prefetches stay in flight ACROSS the barrier.
// LDS segments (bytes): seg(layer,p) = (layer*2+p)*16384; 64 KiB total.
// element (row,col) of seg: byte = row*256 + (((col>>3)^(row&15))<<4) + (col&7)*2
// ---------------------------------------------------------------------------
__global__ __launch_bounds__(512) void lstm_fused(
    const float* __restrict__ x,
    const float* __restrict__ b_ih_l0, const float* __restrict__ b_hh_l0,
    const float* __restrict__ b_ih_l1, const float* __restrict__ b_hh_l1,
    const float* __restrict__ fc_w, const float* __restrict__ fc_b,
    const unsigned short* __restrict__ W0f, const unsigned short* __restrict__ W1f,
    float* __restrict__ out) {
  __shared__ __align__(16) char hls[4 * 16384];

  const int tid = (int)threadIdx.x;
  const int wv = tid >> 6;          // wave 0..7 = n-slice
  const int lane = tid & 63;
  const int lr = lane & 15;         // A: m-row / B: n-col / D: col
  const int lq = lane >> 4;         // k-quad / D row group
  const int b0 = (int)blockIdx.x * 64;

  for (int i = tid; i < 16384; i += 512) ((unsigned*)hls)[i] = 0u;

  // Premultiplied bias scalars: q0/q1/q3 -> -L1*b, q2 -> +L2*b.
  const float L1 = 1.44269504f, L2 = 2.88539008f;
  float nb0[4], nb1[4];
#pragma unroll
  for (int q = 0; q < 4; ++q) {
    int g = q * 128 + wv * 16 + lr;
    float s0 = b_ih_l0[g] + b_hh_l0[g];
    float s1 = b_ih_l1[g] + b_hh_l1[g];
    float sc = (q == 2) ? L2 : -L1;
    nb0[q] = sc * s0;
    nb1[q] = sc * s1;
  }
  const f32x4 zero4 = {0.0f, 0.0f, 0.0f, 0.0f};

  // Read base (A-frag, row m*16+lr, k-chunk kc): addr = (rbB+seg) ^ (kc<<6) + m*4096
  const unsigned rbB = (unsigned)(lr * 256 + ((lq ^ lr) << 4));
  // Write base (D elem row m*16+lq*4+r): addr = (wbB+seg) ^ (r<<4) + m*4096 + r*256
  const unsigned cwl = (unsigned)((wv * 2 + (lr >> 3)) ^ (lq << 2));
  const unsigned wbB = (unsigned)(lq * 1024 + (cwl << 4) + (lr & 7) * 2);
  // Weight byte-offset bases (32-bit; q/kc strides are compile-time).
  const unsigned wB0 = (unsigned)((wv * 320 + lane) * 16);
  const unsigned wB1 = (unsigned)((wv * 512 + lane) * 16);
  const unsigned xo0 = (unsigned)(((b0 + lr) * 784 + lq * 8) * 4);

  float c0s[4][4], c1s[4][4];   // [m][r]
#pragma unroll
  for (int m = 0; m < 4; ++m)
#pragma unroll
    for (int r = 0; r < 4; ++r) { c0s[m][r] = 0.0f; c1s[m][r] = 0.0f; }

  // Prefetch state. xu: x_t fragments (lq==3 upper half stays zero = k-pad).
  // pw0: L0 kc0 weight frags (depth 1 — R6 showed depth 2 buys nothing).
  f32x4 xu0[4], xu1[4];
  short8 pw0[4];
#pragma unroll
  for (int m = 0; m < 4; ++m) {
    const char* xb = (const char*)x;
    const unsigned xo = xo0 + (unsigned)(m * 50176);
    xu0[m] = *(const f32x4*)(xb + xo);
    f32x4 z = {0.0f, 0.0f, 0.0f, 0.0f};
    xu1[m] = z;
    if (lq < 3) xu1[m] = *(const f32x4*)(xb + xo + 16);
  }
#pragma unroll
  for (int q = 0; q < 4; ++q)
    pw0[q] = *(const short8*)((const char*)W0f + (wB0 + (unsigned)(q * 40960)));

  __syncthreads();

  for (int t = 0; t < 28; ++t) {
    const unsigned sp = (unsigned)(t & 1) << 14;   // seg offset, parity p
    const unsigned sq = sp ^ 16384u;               // parity 1-p

    // ---------------- layer 0: gates = [x_t | h0(t-1)] @ W0^T (+b in epi) --
    f32x4 acc[4][4];   // [m][q]

    // kc = 0 (peeled): A = prefetched x_t fragment; B = prefetched pw0.
    {
      short8 ax[4];
#pragma unroll
      for (int m = 0; m < 4; ++m) {
        u32x4 up;
        up[0] = cvtpk(xu0[m][0], xu0[m][1]);
        up[1] = cvtpk(xu0[m][2], xu0[m][3]);
        up[2] = cvtpk(xu1[m][0], xu1[m][1]);
        up[3] = cvtpk(xu1[m][2], xu1[m][3]);
        ax[m] = __builtin_bit_cast(short8, up);
      }
#pragma unroll
      for (int m = 0; m < 4; ++m)
#pragma unroll
        for (int q = 0; q < 4; ++q) acc[m][q] = MFMA16(ax[m], pw0[q], zero4);
    }

    // kc = 1..4: A = h0(t-1) from LDS seg(0,1-p)
    {
      const unsigned r0 = rbB + sq;
#pragma unroll 2
      for (int kc = 1; kc < 5; ++kc) {
        short8 bq[4];
#pragma unroll
        for (int q = 0; q < 4; ++q)
          bq[q] = *(const short8*)((const char*)W0f + (wB0 + (unsigned)(q * 40960 + kc * 1024)));
        short8 am[4];
#pragma unroll
        for (int m = 0; m < 4; ++m)
          am[m] = *(const short8*)(hls + ((r0 ^ (unsigned)((kc - 1) * 64)) + m * 4096));
#pragma unroll
        for (int m = 0; m < 4; ++m)
#pragma unroll
          for (int q = 0; q < 4; ++q) acc[m][q] = MFMA16(am[m], bq[q], acc[m][q]);
      }
    }

    // Prefetch L1 kc=0 weights NOW: the trans-heavy L0 epilogue below covers
    // the L2 latency; with BAR_LDS they may stay in flight across the barrier.
    short8 pq[4];
#pragma unroll
    for (int q = 0; q < 4; ++q)
      pq[q] = *(const short8*)((const char*)W1f + (wB1 + (unsigned)(q * 65536)));

    // layer 0 epilogue -> h0(t) into seg(0,p)
    {
      const unsigned wa = wbB + sp;
#pragma unroll
      for (int m = 0; m < 4; ++m) {
        float hv[4];
#pragma unroll
        for (int r = 0; r < 4; ++r) {
          float c = c0s[m][r], h;
          lstm_elem(acc[m][0][r], acc[m][1][r], acc[m][2][r], acc[m][3][r],
                    nb0[0], nb0[1], nb0[2], nb0[3], c, h);
          c0s[m][r] = c; hv[r] = h;
        }
        unsigned u01 = cvtpk(hv[0], hv[1]);
        unsigned u23 = cvtpk(hv[2], hv[3]);
        *(unsigned short*)(hls + ((wa ^ 0u)  + m * 4096 + 0))   = (unsigned short)u01;
        *(unsigned short*)(hls + ((wa ^ 16u) + m * 4096 + 256)) = (unsigned short)(u01 >> 16);
        *(unsigned short*)(hls + ((wa ^ 32u) + m * 4096 + 512)) = (unsigned short)u23;
        *(unsigned short*)(hls + ((wa ^ 48u) + m * 4096 + 768)) = (unsigned short)(u23 >> 16);
      }
    }

    BAR_LDS();   // h0(t) visible; also covers all h1 double-buffer hazards.
                 // lgkm-only drain: global prefetches stay in flight.

    // ---------------- layer 1: gates = [h0(t) | h1(t-1)] @ W1^T (+b) -------
    {
      const unsigned rh0 = rbB + sp;             // h0(t): seg(0,p)
      const unsigned rh1 = rbB + 32768u + sq;    // h1(t-1): seg(1,1-p)

      // kc = 0 (peeled): B = prefetched pq; C = zero4
      {
        short8 am[4];
#pragma unroll
        for (int m = 0; m < 4; ++m)
          am[m] = *(const short8*)(hls + (rh0 + m * 4096));
#pragma unroll
        for (int m = 0; m < 4; ++m)
#pragma unroll
          for (int q = 0; q < 4; ++q) acc[m][q] = MFMA16(am[m], pq[q], zero4);
      }
#pragma unroll 2
      for (int kc = 1; kc < 4; ++kc) {
        short8 bq[4];
#pragma unroll
        for (int q = 0; q < 4; ++q)
          bq[q] = *(const short8*)((const char*)W1f + (wB1 + (unsigned)(q * 65536 + kc * 1024)));
        short8 am[4];
#pragma unroll
        for (int m = 0; m < 4; ++m)
          am[m] = *(const short8*)(hls + ((rh0 ^ (unsigned)(kc * 64)) + m * 4096));
#pragma unroll
        for (int m = 0; m < 4; ++m)
#pragma unroll
          for (int q = 0; q < 4; ++q) acc[m][q] = MFMA16(am[m], bq[q], acc[m][q]);
      }
#pragma unroll 2
      for (int kc = 4; kc < 8; ++kc) {
        short8 bq[4];
#pragma unroll
        for (int q = 0; q < 4; ++q)
          bq[q] = *(const short8*)((const char*)W1f + (wB1 + (unsigned)(q * 65536 + kc * 1024)));
        short8 am[4];
#pragma unroll
        for (int m = 0; m < 4; ++m)
          am[m] = *(const short8*)(hls + ((rh1 ^ (unsigned)((kc - 4) * 64)) + m * 4096));
#pragma unroll
        for (int m = 0; m < 4; ++m)
#pragma unroll
          for (int q = 0; q < 4; ++q) acc[m][q] = MFMA16(am[m], bq[q], acc[m][q]);
      }
    }

    // layer 1 epilogue -> h1(t) into seg(1,p), with next-t prefetches issued
    // after the first half (acc[0..1] dead by then -> bounded reg peak).
    {
      const unsigned wa = wbB + 32768u + sp;
#pragma unroll
      for (int m = 0; m < 2; ++m) {
        float hv[4];
#pragma unroll
        for (int r = 0; r < 4; ++r) {
          float c = c1s[m][r], h;
          lstm_elem(acc[m][0][r], acc[m][1][r], acc[m][2][r], acc[m][3][r],
                    nb1[0], nb1[1], nb1[2], nb1[3], c, h);
          c1s[m][r] = c; hv[r] = h;
        }
        unsigned u01 = cvtpk(hv[0], hv[1]);
        unsigned u23 = cvtpk(hv[2], hv[3]);
        *(unsigned short*)(hls + ((wa ^ 0u)  + m * 4096 + 0))   = (unsigned short)u01;
        *(unsigned short*)(hls + ((wa ^ 16u) + m * 4096 + 256)) = (unsigned short)(u01 >> 16);
        *(unsigned short*)(hls + ((wa ^ 32u) + m * 4096 + 512)) = (unsigned short)u23;
        *(unsigned short*)(hls + ((wa ^ 48u) + m * 4096 + 768)) = (unsigned short)(u23 >> 16);
      }

      // ---- next-t prefetch: x fragments + L0 kc=0 weights (covered by the
      // remaining half-epilogue; at t=27 re-reads t=27, harmless).
      {
        const int tn = (t < 27) ? t + 1 : 27;
        const char* xb = (const char*)x + (unsigned)(tn * 112);
#pragma unroll
        for (int m = 0; m < 4; ++m) {
          const unsigned xo = xo0 + (unsigned)(m * 50176);
          xu0[m] = *(const f32x4*)(xb + xo);
          if (lq < 3) xu1[m] = *(const f32x4*)(xb + xo + 16);
        }
#pragma unroll
        for (int q = 0; q < 4; ++q)
          pw0[q] = *(const short8*)((const char*)W0f + (wB0 + (unsigned)(q * 40960)));
      }

#pragma unroll
      for (int m = 2; m < 4; ++m) {
        float hv[4];
#pragma unroll
        for (int r = 0; r < 4; ++r) {
          float c = c1s[m][r], h;
          lstm_elem(acc[m][0][r], acc[m][1][r], acc[m][2][r], acc[m][3][r],
                    nb1[0], nb1[1], nb1[2], nb1[3], c, h);
          c1s[m][r] = c; hv[r] = h;
        }
        unsigned u01 = cvtpk(hv[0], hv[1]);
        unsigned u23 = cvtpk(hv[2], hv[3]);
        *(unsigned short*)(hls + ((wa ^ 0u)  + m * 4096 + 0))   = (unsigned short)u01;
        *(unsigned short*)(hls + ((wa ^ 16u) + m * 4096 + 256)) = (unsigned short)(u01 >> 16);
        *(unsigned short*)(hls + ((wa ^ 32u) + m * 4096 + 512)) = (unsigned short)u23;
        *(unsigned short*)(hls + ((wa ^ 48u) + m * 4096 + 768)) = (unsigned short)(u23 >> 16);
      }
    }

    BAR_LDS();   // h1(t) visible for next iteration's L1 kc4-7 reads.
  }

  // ---------------- final h_n / c_n stores (hoisted out of the t-loop) -----
  // t=27 parity p=1: h0(27) in seg(0,1) = +16384, h1(27) in seg(1,1) = +49152.
  {
    const unsigned wa0 = wbB + 16384u;
    const unsigned wa1 = wbB + 49152u;
#pragma unroll
    for (int m = 0; m < 4; ++m)
#pragma unroll
      for (int r = 0; r < 4; ++r) {
        int row = m * 16 + lq * 4 + r, col = wv * 16 + lr;
        size_t o = (size_t)(b0 + row) * 128 + col;
        unsigned roff = (unsigned)(r << 4);
        float h0 = bf2f(*(const unsigned short*)(hls + ((wa0 ^ roff) + m * 4096 + r * 256)));
        float h1 = bf2f(*(const unsigned short*)(hls + ((wa1 ^ roff) + m * 4096 + r * 256)));
        out[163840 + o] = h0;            // h_n layer 0
        out[4358144 + o] = c0s[m][r];    // c_n layer 0
        out[2260992 + o] = h1;           // h_n layer 1
        out[6455296 + o] = c1s[m][r];    // c_n layer 1
      }
  }

  __syncthreads();   // cold path: full sync before FC's cross-thread reads

  // ---------------- logits = h1(27) @ fc_w^T + fc_b ------------------------
  // 64 rows x 10 outs = 640 items over 512 threads.
  for (int it = tid; it < 640; it += 512) {
    const unsigned short* h1f = (const unsigned short*)(hls + 49152);
    int bl = it / 10, o = it % 10;
    float s = fc_b[o];
#pragma unroll
    for (int kc8 = 0; kc8 < 16; ++kc8) {
      short8 hv = *(const short8*)(h1f + bl * 128 + ((kc8 ^ (bl & 15)) << 3));
      const float* wp = fc_w + o * 128 + kc8 * 8;
#pragma unroll
      for (int j = 0; j < 8; ++j) s += bf2f((unsigned short)hv[j]) * wp[j];
    }
    out[(size_t)(b0 + bl) * 10 + o] = s;
  }
}

extern "C" void kernel_launch(void* const* d_in, const int* in_sizes, int n_in,
                              void* d_out, int out_size, void* d_ws, size_t ws_size,
                              hipStream_t stream) {
  const float* x       = (const float*)d_in[0];
  const float* w_ih_l0 = (const float*)d_in[1];
  const float* w_hh_l0 = (const float*)d_in[2];
  const float* b_ih_l0 = (const float*)d_in[3];
  const float* b_hh_l0 = (const float*)d_in[4];
  const float* w_ih_l1 = (const float*)d_in[5];
  const float* w_hh_l1 = (const float*)d_in[6];
  const float* b_ih_l1 = (const float*)d_in[7];
  const float* b_hh_l1 = (const float*)d_in[8];
  const float* fc_w    = (const float*)d_in[9];
  const float* fc_b    = (const float*)d_in[10];

  unsigned short* W0f = (unsigned short*)d_ws;            // 32*5*64*8 = 81920 ush
  unsigned short* W1f = W0f + 32 * 5 * 64 * 8;            // 32*8*64*8 = 131072 ush
  float* out = (float*)d_out;

  hipLaunchKernelGGL(prep_weights, dim3(104), dim3(256), 0, stream,
                     w_ih_l0, w_hh_l0, w_ih_l1, w_hh_l1, W0f, W1f);
  hipLaunchKernelGGL(lstm_fused, dim3(256), dim3(512), 0, stream,
                     x, b_ih_l0, b_hh_l0, b_ih_l1, b_hh_l1, fc_w, fc_b, W0f, W1f, out);
}